// Round 1
// baseline (522.024 us; speedup 1.0000x reference)
//
#include <hip/hip_runtime.h>

#define VOCABSZ 30522
#define EMB 768
#define HD 1024
#define D3 128
#define CTXN 512
#define BB 8
#define SS 64

__device__ __forceinline__ float fast_tanh(float x) {
  float e = __expf(2.f * x);
  return 1.f - 2.f * __builtin_amdgcn_rcpf(e + 1.f);
}

// ---------------- kpre: Wc = W_in @ W_att_in[:1024], qb = b_in@Wa_top + b_att_in
__global__ __launch_bounds__(256) void kpre(const float* __restrict__ W_in,
                                            const float* __restrict__ b_in,
                                            const float* __restrict__ W_att_in,
                                            const float* __restrict__ b_att_in,
                                            float* __restrict__ Wc,
                                            float* __restrict__ qb) {
  int blk = blockIdx.x;
  int tid = threadIdx.x;
  if (blk == 96) {
    if (tid < 128) {
      int d = tid;
      float acc = b_att_in[d];
      for (int k = 0; k < HD; ++k) acc += b_in[k] * W_att_in[k * D3 + d];
      qb[d] = acc;
    }
    return;
  }
  int r0 = blk * 8;
  int d = tid & 127, rh = tid >> 7;  // rh in {0,1}: rows rh*4 .. rh*4+4
  __shared__ float lw[8][128];
  float acc[4] = {0.f, 0.f, 0.f, 0.f};
  for (int kc = 0; kc < 8; ++kc) {
    __syncthreads();
    for (int i = tid; i < 8 * 128; i += 256) {
      int r = i >> 7, k = i & 127;
      lw[r][k] = W_in[(r0 + r) * HD + kc * 128 + k];
    }
    __syncthreads();
    for (int k = 0; k < 128; ++k) {
      float w = W_att_in[(kc * 128 + k) * D3 + d];
#pragma unroll
      for (int r = 0; r < 4; ++r) acc[r] = fmaf(lw[rh * 4 + r][k], w, acc[r]);
    }
  }
#pragma unroll
  for (int r = 0; r < 4; ++r) Wc[(r0 + rh * 4 + r) * D3 + d] = acc[r];
}

// ---------------- kctx: ctx_proj[b][c][d] = context[b][c][:] @ W_att_h[:, d] + b_att_h[d]
__global__ __launch_bounds__(256) void kctx(const float* __restrict__ context,
                                            const float* __restrict__ W_att_h,
                                            const float* __restrict__ b_att_h,
                                            float* __restrict__ ctxp) {
  int blk = blockIdx.x;            // 8 b * 32 ctiles
  int b = blk >> 5, ct = blk & 31;
  int c0 = ct * 16;
  int tid = threadIdx.x;
  int d = tid & 127, ch = tid >> 7;  // ch: c rows ch*8 .. +8
  __shared__ float lc[16][132];
  float acc[8] = {0.f, 0.f, 0.f, 0.f, 0.f, 0.f, 0.f, 0.f};
  for (int kc = 0; kc < 8; ++kc) {
    __syncthreads();
    for (int i = tid; i < 16 * 128; i += 256) {
      int c = i >> 7, k = i & 127;
      lc[c][k] = context[((long)b * CTXN + c0 + c) * HD + kc * 128 + k];
    }
    __syncthreads();
    for (int k4 = 0; k4 < 32; ++k4) {
      int kk = kc * 128 + k4 * 4;
      float w0 = W_att_h[(kk + 0) * D3 + d];
      float w1 = W_att_h[(kk + 1) * D3 + d];
      float w2 = W_att_h[(kk + 2) * D3 + d];
      float w3 = W_att_h[(kk + 3) * D3 + d];
#pragma unroll
      for (int c = 0; c < 8; ++c) {
        const float4 cv = *reinterpret_cast<const float4*>(&lc[ch * 8 + c][k4 * 4]);
        acc[c] = fmaf(cv.x, w0, acc[c]);
        acc[c] = fmaf(cv.y, w1, acc[c]);
        acc[c] = fmaf(cv.z, w2, acc[c]);
        acc[c] = fmaf(cv.w, w3, acc[c]);
      }
    }
  }
  float bb = b_att_h[d];
#pragma unroll
  for (int c = 0; c < 8; ++c)
    ctxp[((long)b * CTXN + c0 + ch * 8 + c) * D3 + d] = acc[c] + bb;
}

// ---------------- kstep: h_new[b][j] = sum_k h_old[b][k] * W_s[k][j] + b_s[j]
__global__ __launch_bounds__(256) void kstep(const float* __restrict__ hsrc,
                                             int hsrc_is_ctx,
                                             const float* __restrict__ W_s,
                                             const float* __restrict__ b_s,
                                             float* __restrict__ hdst) {
  int j0 = blockIdx.x * 8;  // 128 blocks x 8 columns
  int tid = threadIdx.x;
  __shared__ float hl[8 * 1056];    // swizzled: idx = b*1056 + k + (k>>5)
  __shared__ float sacc[32 * 65];
  for (int i = tid; i < BB * HD; i += 256) {
    int b = i >> 10, k = i & 1023;
    float v = hsrc_is_ctx ? hsrc[((long)b * CTXN + (CTXN - 1)) * HD + k]
                          : hsrc[b * HD + k];
    hl[b * 1056 + k + (k >> 5)] = v;
  }
  __syncthreads();
  int jl = tid & 7, kc = tid >> 3;  // kc 0..31, 32 k's each
  float acc[8] = {0.f, 0.f, 0.f, 0.f, 0.f, 0.f, 0.f, 0.f};
  int kb = kc * 33;                 // swizzled base: k + (k>>5) = kc*33 + i
  for (int i = 0; i < 32; ++i) {
    int k = kc * 32 + i;
    float w = W_s[(long)k * HD + j0 + jl];
#pragma unroll
    for (int b = 0; b < 8; ++b)
      acc[b] = fmaf(hl[b * 1056 + kb + i], w, acc[b]);
  }
#pragma unroll
  for (int b = 0; b < 8; ++b) sacc[kc * 65 + jl * 8 + b] = acc[b];
  __syncthreads();
  if (tid < 64) {
    int jj = tid >> 3, b = tid & 7;
    float s = 0.f;
    for (int kk = 0; kk < 32; ++kk) s += sacc[kk * 65 + jj * 8 + b];
    hdst[b * HD + j0 + jj] = s + b_s[j0 + jj];
  }
}

// ---------------- kqf: q[t][b][d] = feats@Wc + h_t@W_att_in[1024:] + qb
__global__ __launch_bounds__(256) void kqf(const int* __restrict__ ids,
                                           const float* __restrict__ emb,
                                           const float* __restrict__ Wc,
                                           const float* __restrict__ W_att_in,
                                           const float* __restrict__ qb,
                                           const float* __restrict__ h_all,
                                           float* __restrict__ q) {
  int blk = blockIdx.x;             // 256: b*32 + tpair
  int b = blk >> 5, tp = blk & 31;
  int tid = threadIdx.x;
  __shared__ float lf[2][768];
  __shared__ float lh[2][1024];
  __shared__ float red[2][2][128];
  for (int u = 0; u < 2; ++u) {
    int t = tp * 2 + u;
    int id = ids[b * SS + t];
    for (int i = tid; i < EMB; i += 256) lf[u][i] = emb[(long)id * EMB + i];
    for (int i = tid; i < HD; i += 256) lh[u][i] = h_all[((long)t * BB + b) * HD + i];
  }
  __syncthreads();
  int d = tid & 127, kh = tid >> 7;
  float acc0 = 0.f, acc1 = 0.f;
  for (int k = kh * 384; k < kh * 384 + 384; ++k) {
    float w = Wc[k * D3 + d];
    acc0 = fmaf(lf[0][k], w, acc0);
    acc1 = fmaf(lf[1][k], w, acc1);
  }
  for (int k = kh * 512; k < kh * 512 + 512; ++k) {
    float w = W_att_in[(HD + k) * D3 + d];
    acc0 = fmaf(lh[0][k], w, acc0);
    acc1 = fmaf(lh[1][k], w, acc1);
  }
  red[0][kh][d] = acc0;
  red[1][kh][d] = acc1;
  __syncthreads();
  if (kh == 0) {
    float base = qb[d];
    int t = tp * 2;
    q[((t)*BB + b) * D3 + d] = red[0][0][d] + red[0][1][d] + base;
    q[((t + 1) * BB + b) * D3 + d] = red[1][0][d] + red[1][1][d] + base;
  }
}

// ---------------- katt: out[b][t][c] = sum_d V[d]*tanh(q[t][b][d] + ctxp[b][c][d])
__global__ __launch_bounds__(256) void katt(const float* __restrict__ q,
                                            const float* __restrict__ ctxp,
                                            const float* __restrict__ V,
                                            float* __restrict__ out) {
  int blk = blockIdx.x;             // b(8) x tt(2) x ct(16)
  int b = blk >> 5, tt = (blk >> 4) & 1, ct = blk & 15;
  int t0 = tt * 32, c0 = ct * 32;
  int tid = threadIdx.x;
  __shared__ float lq[32][128];
  __shared__ float lc[32][132];
  __shared__ float lv[128];
  for (int i = tid; i < 32 * 128; i += 256) {
    int r = i >> 7, d = i & 127;
    lq[r][d] = q[((long)(t0 + r) * BB + b) * D3 + d];
    lc[r][d] = ctxp[((long)b * CTXN + c0 + r) * D3 + d];
  }
  if (tid < 128) lv[tid] = V[tid];
  __syncthreads();
  int cl = tid & 31, tg = tid >> 5;  // tg 0..7; t = tg + u*8
  float r[4] = {0.f, 0.f, 0.f, 0.f};
  for (int d4 = 0; d4 < 32; ++d4) {
    float4 cv = *reinterpret_cast<const float4*>(&lc[cl][d4 * 4]);
    float4 vv = *reinterpret_cast<const float4*>(&lv[d4 * 4]);
#pragma unroll
    for (int u = 0; u < 4; ++u) {
      int t = tg + u * 8;
      float4 qv = *reinterpret_cast<const float4*>(&lq[t][d4 * 4]);
      r[u] = fmaf(vv.x, fast_tanh(qv.x + cv.x), r[u]);
      r[u] = fmaf(vv.y, fast_tanh(qv.y + cv.y), r[u]);
      r[u] = fmaf(vv.z, fast_tanh(qv.z + cv.z), r[u]);
      r[u] = fmaf(vv.w, fast_tanh(qv.w + cv.w), r[u]);
    }
  }
#pragma unroll
  for (int u = 0; u < 4; ++u) {
    int t = tg + u * 8;
    out[((long)b * SS + (t0 + t)) * CTXN + c0 + cl] = r[u];
  }
  if (blk == 0) {
    for (int i = tid; i < SS * BB; i += 256) out[(long)BB * SS * CTXN + i] = 0.f;
  }
}

extern "C" void kernel_launch(void* const* d_in, const int* in_sizes, int n_in,
                              void* d_out, int out_size, void* d_ws, size_t ws_size,
                              hipStream_t stream) {
  const int* ids = (const int*)d_in[0];
  const float* context = (const float*)d_in[4];
  const float* emb = (const float*)d_in[5];
  const float* W_in = (const float*)d_in[6];
  const float* b_in = (const float*)d_in[7];
  const float* W_s = (const float*)d_in[8];
  const float* b_s = (const float*)d_in[9];
  const float* W_att_in = (const float*)d_in[10];
  const float* b_att_in = (const float*)d_in[11];
  const float* W_att_h = (const float*)d_in[12];
  const float* b_att_h = (const float*)d_in[13];
  const float* V = (const float*)d_in[14];

  float* ws = (float*)d_ws;
  float* Wc = ws;                    // 768*128   = 98304
  float* qb = Wc + 98304;            // 128
  float* q = qb + 128;               // 64*8*128  = 65536
  float* ctxp = q + 65536;           // 8*512*128 = 524288
  float* h_all = ctxp + 524288;      // 64*8*1024 = 524288
  float* out = (float*)d_out;

  hipLaunchKernelGGL(kpre, dim3(97), dim3(256), 0, stream, W_in, b_in, W_att_in,
                     b_att_in, Wc, qb);
  hipLaunchKernelGGL(kctx, dim3(256), dim3(256), 0, stream, context, W_att_h,
                     b_att_h, ctxp);
  for (int t = 0; t < SS; ++t) {
    const float* hsrc = (t == 0) ? context : (h_all + (long)(t - 1) * BB * HD);
    hipLaunchKernelGGL(kstep, dim3(128), dim3(256), 0, stream, hsrc,
                       (t == 0) ? 1 : 0, W_s, b_s, h_all + (long)t * BB * HD);
  }
  hipLaunchKernelGGL(kqf, dim3(256), dim3(256), 0, stream, ids, emb, Wc,
                     W_att_in, qb, h_all, q);
  hipLaunchKernelGGL(katt, dim3(256), dim3(256), 0, stream, q, ctxp, V, out);
}